// Round 4
// baseline (618.577 us; speedup 1.0000x reference)
//
#include <hip/hip_runtime.h>
#include <stdint.h>

#define NB 4
#define NS 2048
#define NE 1024
#define NH 16
#define ND 64

typedef __attribute__((ext_vector_type(8))) short short8;
typedef __attribute__((ext_vector_type(4))) float f32x4;
typedef __attribute__((ext_vector_type(4))) unsigned short us4;

__device__ __forceinline__ unsigned short f2bf(float f) {
    unsigned u = __builtin_bit_cast(unsigned, f);
    u += 0x7FFFu + ((u >> 16) & 1u);   // round-to-nearest-even
    return (unsigned short)(u >> 16);
}

// ---------------- weight fp32 -> bf16 convert (1M elems per launch) ----------------
__global__ __launch_bounds__(256) void cvt_w_kernel(const float* __restrict__ src,
                                                    unsigned short* __restrict__ dst) {
    int i = (blockIdx.x * 256 + threadIdx.x) * 4;
    f32x4 f = *(const f32x4*)(src + i);
    us4 o;
#pragma unroll
    for (int j = 0; j < 4; ++j) o[j] = f2bf(f[j]);
    *(us4*)(dst + i) = o;
}

// ---------------- GEMM: C[M,N] = A[M,K] @ W[N,K]^T ----------------
// M=8192, N=1024, K=1024. 128x128 tile, BK=32, 4 waves (each 64x64).
// A_IS_F32: A is fp32 (converted to bf16 during LDS staging), else bf16.
// OUT_MODE 0: write bf16 to [B,H,S,D] head-major layout (n = h*64+d).
// OUT_MODE 1: write fp32 to [M,N] with bias add.
// OUT_MODE 2: write bf16 TRANSPOSED per head: [B,H,D,S] (for V), packed us4.
template<int A_IS_F32, int OUT_MODE>
__global__ __launch_bounds__(256) void gemm_bt(const void* __restrict__ Aptr,
                                               const unsigned short* __restrict__ Wp,
                                               void* __restrict__ Cp,
                                               const float* __restrict__ bias) {
    constexpr int K = 1024;
    __shared__ unsigned short As[128][40];  // pad 32->40: row stride 20 dwords -> 2-way (free)
    __shared__ unsigned short Bs[128][40];
    const int tid = threadIdx.x;
    const int bm = blockIdx.x, bn = blockIdx.y;
    const int lane = tid & 63, wid = tid >> 6;
    const int lr = lane & 15, lg = lane >> 4;
    const int wr = wid >> 1, wc = wid & 1;
    const int srow = tid >> 1, shalf = tid & 1;

    f32x4 acc[4][4];
#pragma unroll
    for (int a = 0; a < 4; ++a)
#pragma unroll
        for (int b = 0; b < 4; ++b) acc[a][b] = (f32x4){0.f, 0.f, 0.f, 0.f};

    const size_t arow = (size_t)(bm * 128 + srow) * K + shalf * 16;
    const size_t brow = (size_t)(bn * 128 + srow) * K + shalf * 16;

    for (int k0 = 0; k0 < K; k0 += 32) {
        __syncthreads();  // protect previous iteration's fragment reads
        if (A_IS_F32) {
            const float* ap = (const float*)Aptr + arow + k0;
            f32x4 a0 = *(const f32x4*)(ap);
            f32x4 a1 = *(const f32x4*)(ap + 4);
            f32x4 a2 = *(const f32x4*)(ap + 8);
            f32x4 a3 = *(const f32x4*)(ap + 12);
            short8 p0, p1;
#pragma unroll
            for (int j = 0; j < 4; ++j) {
                p0[j]     = (short)f2bf(a0[j]);
                p0[j + 4] = (short)f2bf(a1[j]);
                p1[j]     = (short)f2bf(a2[j]);
                p1[j + 4] = (short)f2bf(a3[j]);
            }
            *(short8*)&As[srow][shalf * 16]     = p0;
            *(short8*)&As[srow][shalf * 16 + 8] = p1;
        } else {
            const unsigned short* ap = (const unsigned short*)Aptr + arow + k0;
            short8 a0 = *(const short8*)(ap);
            short8 a1 = *(const short8*)(ap + 8);
            *(short8*)&As[srow][shalf * 16]     = a0;
            *(short8*)&As[srow][shalf * 16 + 8] = a1;
        }
        {
            const unsigned short* bp = Wp + brow + k0;
            short8 b0 = *(const short8*)(bp);
            short8 b1 = *(const short8*)(bp + 8);
            *(short8*)&Bs[srow][shalf * 16]     = b0;
            *(short8*)&Bs[srow][shalf * 16 + 8] = b1;
        }
        __syncthreads();

        short8 af[4], bfr[4];
#pragma unroll
        for (int mi = 0; mi < 4; ++mi) af[mi]  = *(const short8*)&As[wr * 64 + mi * 16 + lr][lg * 8];
#pragma unroll
        for (int ni = 0; ni < 4; ++ni) bfr[ni] = *(const short8*)&Bs[wc * 64 + ni * 16 + lr][lg * 8];
#pragma unroll
        for (int mi = 0; mi < 4; ++mi)
#pragma unroll
            for (int ni = 0; ni < 4; ++ni)
                acc[mi][ni] = __builtin_amdgcn_mfma_f32_16x16x32_bf16(af[mi], bfr[ni], acc[mi][ni], 0, 0, 0);
    }

#pragma unroll
    for (int mi = 0; mi < 4; ++mi) {
#pragma unroll
        for (int ni = 0; ni < 4; ++ni) {
            const int n = bn * 128 + wc * 64 + ni * 16 + lr;
            if (OUT_MODE == 2) {
                // V: write [B,H,D,S]; i -> s consecutive, pack 4 bf16 into one 8B store.
                const int m0 = bm * 128 + wr * 64 + mi * 16 + lg * 4;
                const int b = m0 >> 11, s0 = m0 & 2047;
                const int h = n >> 6, d = n & 63;
                us4 pk;
#pragma unroll
                for (int i = 0; i < 4; ++i) pk[i] = f2bf(acc[mi][ni][i]);
                *(us4*)&((unsigned short*)Cp)[(((size_t)b * NH + h) * ND + d) * NS + s0] = pk;
            } else {
#pragma unroll
                for (int i = 0; i < 4; ++i) {
                    const int m = bm * 128 + wr * 64 + mi * 16 + lg * 4 + i;
                    const float val = acc[mi][ni][i];
                    if (OUT_MODE == 0) {
                        const int b = m >> 11, s = m & 2047, h = n >> 6, d = n & 63;
                        ((unsigned short*)Cp)[(((size_t)b * NH + h) * NS + s) * ND + d] = f2bf(val);
                    } else {
                        ((float*)Cp)[(size_t)m * 1024 + n] = val + bias[n];
                    }
                }
            }
        }
    }
}

// ---------------- flash attention (swapped-operand, barrier-free) ----------------
// grid (S/64, B*H), 256 threads, wave w owns q rows q0+w*16..+15. NO __syncthreads:
// K and V fragments are loaded directly from global (per-head K/V = 256 KB each,
// L1/L2-resident; all 4 waves of a block read IDENTICAL fragment addresses so L1
// provides the sharing LDS staging used to). Only LDS use: per-wave P round-trip.
// q,k layout: [B,H,S,D] bf16. vt layout: [B,H,D,S] bf16 (pre-transposed).
//   S^T = mfma(K_frag, Q_frag):   C col = q = lane&15, row = kv = 16t + (lane>>4)*4 + i
//   O^T = mfma(Vt_frag, P^T_frag): C col = q = lane&15, row = d = 16n + (lane>>4)*4 + i
__global__ __launch_bounds__(256) void attn_kernel(const unsigned short* __restrict__ q,
                                                   const unsigned short* __restrict__ k,
                                                   const unsigned short* __restrict__ vt,
                                                   unsigned short* __restrict__ o) {
    __shared__ unsigned short Pl[4][16][72];   // per-wave P [q][kv]
    const int tid = threadIdx.x;
    const int lane = tid & 63, wid = tid >> 6;
    const int lr = lane & 15, lg = lane >> 4;
    const int bh = blockIdx.y;
    const int q0 = blockIdx.x * 64;
    const size_t base = (size_t)bh * NS * ND;   // same offset for q/k ([B,H,S,D]) and vt ([B,H,D,S])

    // Q fragment (A- and B-operand lane maps coincide): q row = q0+wid*16+lr, k = d
    short8 qf0, qf1;
    {
        const unsigned short* qp = q + base + (size_t)(q0 + wid * 16 + lr) * ND + lg * 8;
        qf0 = *(const short8*)(qp);
        qf1 = *(const short8*)(qp + 32);
    }

    // per-lane fragment base pointers (row picked by lr, 16B chunk by lg)
    const unsigned short* kp = k  + base + (size_t)lr * ND + lg * 8;   // + (kv0+16t)*ND, +32 for d-hi
    const unsigned short* vp = vt + base + (size_t)lr * NS + lg * 8;   // + 16n*NS + kv0, +32 for kv-hi

    float m_run = -__builtin_inff(), l_run = 0.f;   // state for q = lr (replicated over lg)
    f32x4 oa[4];
#pragma unroll
    for (int n = 0; n < 4; ++n) oa[n] = (f32x4){0.f, 0.f, 0.f, 0.f};

    for (int kv0 = 0; kv0 < NS; kv0 += 64) {
        // K fragments: row kv = kv0+16t+lr, d-halves at lg*8 and 32+lg*8
        short8 kf0[4], kf1[4];
#pragma unroll
        for (int t = 0; t < 4; ++t) {
            const unsigned short* kr = kp + (size_t)(kv0 + 16 * t) * ND;
            kf0[t] = *(const short8*)(kr);
            kf1[t] = *(const short8*)(kr + 32);
        }
        // V fragments: row d = 16n+lr, kv-halves at kv0+lg*8 and kv0+32+lg*8
        short8 vf0[4], vf1[4];
#pragma unroll
        for (int n = 0; n < 4; ++n) {
            const unsigned short* vr = vp + (size_t)(16 * n) * NS + kv0;
            vf0[n] = *(const short8*)(vr);
            vf1[n] = *(const short8*)(vr + 32);
        }

        // S^T = K·Q^T : per lane 16 kv values for its own q-row
        f32x4 st[4];
#pragma unroll
        for (int t = 0; t < 4; ++t) st[t] = (f32x4){0.f, 0.f, 0.f, 0.f};
#pragma unroll
        for (int t = 0; t < 4; ++t) {
            st[t] = __builtin_amdgcn_mfma_f32_16x16x32_bf16(kf0[t], qf0, st[t], 0, 0, 0);
            st[t] = __builtin_amdgcn_mfma_f32_16x16x32_bf16(kf1[t], qf1, st[t], 0, 0, 0);
        }

        // online softmax (scalar state, 2 shfl per reduction)
        float pm = st[0][0];
#pragma unroll
        for (int t = 0; t < 4; ++t)
#pragma unroll
            for (int i = 0; i < 4; ++i) pm = fmaxf(pm, st[t][i]);
        pm = fmaxf(pm, __shfl_xor(pm, 16, 64));
        pm = fmaxf(pm, __shfl_xor(pm, 32, 64));
        const float mn = fmaxf(m_run, pm);
        const float alpha = __expf(m_run - mn);
        m_run = mn;
        float rs = 0.f;
#pragma unroll
        for (int t = 0; t < 4; ++t)
#pragma unroll
            for (int i = 0; i < 4; ++i) {
                float p = __expf(st[t][i] - mn);
                st[t][i] = p;
                rs += p;
            }
        rs += __shfl_xor(rs, 16, 64);
        rs += __shfl_xor(rs, 32, 64);
        l_run = l_run * alpha + rs;
#pragma unroll
        for (int n = 0; n < 4; ++n)
#pragma unroll
            for (int i = 0; i < 4; ++i) oa[n][i] *= alpha;

        // P[q=lr][kv] -> per-wave LDS, packed 8B writes (kv = 16t+4lg+i contiguous in i)
#pragma unroll
        for (int t = 0; t < 4; ++t) {
            us4 pk;
#pragma unroll
            for (int i = 0; i < 4; ++i) pk[i] = f2bf(st[t][i]);
            *(us4*)&Pl[wid][lr][t * 16 + lg * 4] = pk;
        }
        short8 pf0 = *(const short8*)&Pl[wid][lr][lg * 8];
        short8 pf1 = *(const short8*)&Pl[wid][lr][32 + lg * 8];

        // O^T += V^T · P^T
#pragma unroll
        for (int n = 0; n < 4; ++n) {
            oa[n] = __builtin_amdgcn_mfma_f32_16x16x32_bf16(vf0[n], pf0, oa[n], 0, 0, 0);
            oa[n] = __builtin_amdgcn_mfma_f32_16x16x32_bf16(vf1[n], pf1, oa[n], 0, 0, 0);
        }
    }

    const int b = bh >> 4, h = bh & 15;
    const int s = q0 + wid * 16 + lr;
    const float scl = 0.125f / l_run;   // softmax BEFORE scaling -> /8 here
#pragma unroll
    for (int n = 0; n < 4; ++n) {
        us4 pk;
#pragma unroll
        for (int i = 0; i < 4; ++i) pk[i] = f2bf(oa[n][i] * scl);
        *(us4*)&o[(((size_t)b * NS + s) * NH + h) * ND + n * 16 + lg * 4] = pk;
    }
}

extern "C" void kernel_launch(void* const* d_in, const int* in_sizes, int n_in,
                              void* d_out, int out_size, void* d_ws, size_t ws_size,
                              hipStream_t stream) {
    (void)in_sizes; (void)n_in; (void)out_size; (void)ws_size;
    const float* values  = (const float*)d_in[0];
    const float* keys    = (const float*)d_in[1];
    const float* queries = (const float*)d_in[2];
    const float* Wv = (const float*)d_in[3];
    const float* Wk = (const float*)d_in[4];
    const float* Wq = (const float*)d_in[5];
    const float* Wo = (const float*)d_in[6];
    const float* bo = (const float*)d_in[7];

    uint8_t* ws = (uint8_t*)d_ws;
    const size_t MB = (size_t)1 << 20;
    unsigned short* wvb = (unsigned short*)(ws + 0 * MB);
    unsigned short* wkb = (unsigned short*)(ws + 2 * MB);
    unsigned short* wqb = (unsigned short*)(ws + 4 * MB);
    unsigned short* wob = (unsigned short*)(ws + 6 * MB);
    unsigned short* qb  = (unsigned short*)(ws + 8 * MB);   // [B,H,S,D] bf16, 16 MB
    unsigned short* kb  = (unsigned short*)(ws + 24 * MB);  // [B,H,S,D] bf16
    unsigned short* vtb = (unsigned short*)(ws + 40 * MB);  // [B,H,D,S] bf16 (transposed V)
    unsigned short* ab  = (unsigned short*)(ws + 56 * MB);  // [B,S,H,D] bf16, 16 MB

    cvt_w_kernel<<<1024, 256, 0, stream>>>(Wv, wvb);
    cvt_w_kernel<<<1024, 256, 0, stream>>>(Wk, wkb);
    cvt_w_kernel<<<1024, 256, 0, stream>>>(Wq, wqb);

    dim3 gg(64, 8);  // (M/128, N/128)
    gemm_bt<1, 0><<<gg, 256, 0, stream>>>(queries, wqb, qb,  nullptr);
    gemm_bt<1, 0><<<gg, 256, 0, stream>>>(keys,    wkb, kb,  nullptr);
    gemm_bt<1, 2><<<gg, 256, 0, stream>>>(values,  wvb, vtb, nullptr);

    cvt_w_kernel<<<1024, 256, 0, stream>>>(Wo, wob);

    attn_kernel<<<dim3(32, 64), 256, 0, stream>>>(qb, kb, vtb, ab);

    gemm_bt<0, 1><<<gg, 256, 0, stream>>>(ab, wob, d_out, bo);
}

// Round 6
// 328.645 us; speedup vs baseline: 1.8822x; 1.8822x over previous
//
#include <hip/hip_runtime.h>
#include <stdint.h>

#define NB 4
#define NS 2048
#define NE 1024
#define NH 16
#define ND 64

typedef __attribute__((ext_vector_type(8))) short short8;
typedef __attribute__((ext_vector_type(4))) float f32x4;
typedef __attribute__((ext_vector_type(4))) unsigned short us4;

__device__ __forceinline__ unsigned short f2bf(float f) {
    unsigned u = __builtin_bit_cast(unsigned, f);
    u += 0x7FFFu + ((u >> 16) & 1u);   // round-to-nearest-even
    return (unsigned short)(u >> 16);
}

// ---------------- weight fp32 -> bf16 convert (1M elems per launch) ----------------
__global__ __launch_bounds__(256) void cvt_w_kernel(const float* __restrict__ src,
                                                    unsigned short* __restrict__ dst) {
    int i = (blockIdx.x * 256 + threadIdx.x) * 4;
    f32x4 f = *(const f32x4*)(src + i);
    us4 o;
#pragma unroll
    for (int j = 0; j < 4; ++j) o[j] = f2bf(f[j]);
    *(us4*)(dst + i) = o;
}

// ---------------- GEMM: C[M,N] = A[M,K] @ W[N,K]^T ----------------
// M=8192, N=1024, K=1024. 128x128 tile, BK=32, 4 waves (each 64x64).
// A_IS_F32: A is fp32 (converted to bf16 during LDS staging), else bf16.
// OUT_MODE 0: write bf16 to [B,H,S,D] head-major layout (n = h*64+d).
// OUT_MODE 1: write fp32 to [M,N] with bias add.
// OUT_MODE 2: write bf16 V^T kv-blocked: [B,H,S/64,D,64] (tile-contiguous), packed us4.
template<int A_IS_F32, int OUT_MODE>
__global__ __launch_bounds__(256) void gemm_bt(const void* __restrict__ Aptr,
                                               const unsigned short* __restrict__ Wp,
                                               void* __restrict__ Cp,
                                               const float* __restrict__ bias) {
    constexpr int K = 1024;
    __shared__ unsigned short As[128][40];  // pad 32->40: row stride 20 dwords -> 2-way (free)
    __shared__ unsigned short Bs[128][40];
    const int tid = threadIdx.x;
    const int bm = blockIdx.x, bn = blockIdx.y;
    const int lane = tid & 63, wid = tid >> 6;
    const int lr = lane & 15, lg = lane >> 4;
    const int wr = wid >> 1, wc = wid & 1;
    const int srow = tid >> 1, shalf = tid & 1;

    f32x4 acc[4][4];
#pragma unroll
    for (int a = 0; a < 4; ++a)
#pragma unroll
        for (int b = 0; b < 4; ++b) acc[a][b] = (f32x4){0.f, 0.f, 0.f, 0.f};

    const size_t arow = (size_t)(bm * 128 + srow) * K + shalf * 16;
    const size_t brow = (size_t)(bn * 128 + srow) * K + shalf * 16;

    for (int k0 = 0; k0 < K; k0 += 32) {
        __syncthreads();  // protect previous iteration's fragment reads
        if (A_IS_F32) {
            const float* ap = (const float*)Aptr + arow + k0;
            f32x4 a0 = *(const f32x4*)(ap);
            f32x4 a1 = *(const f32x4*)(ap + 4);
            f32x4 a2 = *(const f32x4*)(ap + 8);
            f32x4 a3 = *(const f32x4*)(ap + 12);
            short8 p0, p1;
#pragma unroll
            for (int j = 0; j < 4; ++j) {
                p0[j]     = (short)f2bf(a0[j]);
                p0[j + 4] = (short)f2bf(a1[j]);
                p1[j]     = (short)f2bf(a2[j]);
                p1[j + 4] = (short)f2bf(a3[j]);
            }
            *(short8*)&As[srow][shalf * 16]     = p0;
            *(short8*)&As[srow][shalf * 16 + 8] = p1;
        } else {
            const unsigned short* ap = (const unsigned short*)Aptr + arow + k0;
            short8 a0 = *(const short8*)(ap);
            short8 a1 = *(const short8*)(ap + 8);
            *(short8*)&As[srow][shalf * 16]     = a0;
            *(short8*)&As[srow][shalf * 16 + 8] = a1;
        }
        {
            const unsigned short* bp = Wp + brow + k0;
            short8 b0 = *(const short8*)(bp);
            short8 b1 = *(const short8*)(bp + 8);
            *(short8*)&Bs[srow][shalf * 16]     = b0;
            *(short8*)&Bs[srow][shalf * 16 + 8] = b1;
        }
        __syncthreads();

        short8 af[4], bfr[4];
#pragma unroll
        for (int mi = 0; mi < 4; ++mi) af[mi]  = *(const short8*)&As[wr * 64 + mi * 16 + lr][lg * 8];
#pragma unroll
        for (int ni = 0; ni < 4; ++ni) bfr[ni] = *(const short8*)&Bs[wc * 64 + ni * 16 + lr][lg * 8];
#pragma unroll
        for (int mi = 0; mi < 4; ++mi)
#pragma unroll
            for (int ni = 0; ni < 4; ++ni)
                acc[mi][ni] = __builtin_amdgcn_mfma_f32_16x16x32_bf16(af[mi], bfr[ni], acc[mi][ni], 0, 0, 0);
    }

#pragma unroll
    for (int mi = 0; mi < 4; ++mi) {
#pragma unroll
        for (int ni = 0; ni < 4; ++ni) {
            const int n = bn * 128 + wc * 64 + ni * 16 + lr;
            if (OUT_MODE == 2) {
                // V^T kv-blocked: [B,H,S/64,D,64]; i -> s consecutive within a 64-block.
                const int m0 = bm * 128 + wr * 64 + mi * 16 + lg * 4;
                const int b = m0 >> 11, s0 = m0 & 2047;
                const int h = n >> 6, d = n & 63;
                us4 pk;
#pragma unroll
                for (int i = 0; i < 4; ++i) pk[i] = f2bf(acc[mi][ni][i]);
                const size_t idx = ((((size_t)b * NH + h) * (NS / 64) + (s0 >> 6)) * ND + d) * 64 + (s0 & 63);
                *(us4*)&((unsigned short*)Cp)[idx] = pk;
            } else {
#pragma unroll
                for (int i = 0; i < 4; ++i) {
                    const int m = bm * 128 + wr * 64 + mi * 16 + lg * 4 + i;
                    const float val = acc[mi][ni][i];
                    if (OUT_MODE == 0) {
                        const int b = m >> 11, s = m & 2047, h = n >> 6, d = n & 63;
                        ((unsigned short*)Cp)[(((size_t)b * NH + h) * NS + s) * ND + d] = f2bf(val);
                    } else {
                        ((float*)Cp)[(size_t)m * 1024 + n] = val + bias[n];
                    }
                }
            }
        }
    }
}

__device__ __forceinline__ void online_sm(f32x4 st[4], float& m_run, float& l_run, f32x4 oa[4]) {
    float pm = st[0][0];
#pragma unroll
    for (int t = 0; t < 4; ++t)
#pragma unroll
        for (int i = 0; i < 4; ++i) pm = fmaxf(pm, st[t][i]);
    pm = fmaxf(pm, __shfl_xor(pm, 16, 64));
    pm = fmaxf(pm, __shfl_xor(pm, 32, 64));
    const float mn = fmaxf(m_run, pm);
    const float alpha = __expf(m_run - mn);
    m_run = mn;
    float rs = 0.f;
#pragma unroll
    for (int t = 0; t < 4; ++t)
#pragma unroll
        for (int i = 0; i < 4; ++i) {
            float p = __expf(st[t][i] - mn);
            st[t][i] = p;
            rs += p;
        }
    rs += __shfl_xor(rs, 16, 64);
    rs += __shfl_xor(rs, 32, 64);
    l_run = l_run * alpha + rs;
#pragma unroll
    for (int n = 0; n < 4; ++n)
#pragma unroll
        for (int i = 0; i < 4; ++i) oa[n][i] *= alpha;
}

// ---------------- flash attention (swapped-operand, QBLK=32/wave) ----------------
// grid (S/128, B*H), 256 threads. Wave w owns q rows q0+w*32 .. +31 (2 fragments A/B).
// q,k layout: [B,H,S,D] bf16. vtt layout: [B,H,S/64,D,64] bf16 (V^T, kv-blocked:
// each 64-kv tile of V^T is one contiguous 8KB chunk -> fully coalesced staging;
// the K tile is naturally contiguous since row length = D = 64).
//   S^T = mfma(K_frag, Q_frag):    C col = q = lane&15, row = kv = 16t + (lane>>4)*4 + i
//   O^T = mfma(Vt_frag, P^T_frag): C col = q = lane&15, row = d  = 16n + (lane>>4)*4 + i
__global__ __launch_bounds__(256) void attn_kernel(const unsigned short* __restrict__ q,
                                                   const unsigned short* __restrict__ k,
                                                   const unsigned short* __restrict__ vtt,
                                                   unsigned short* __restrict__ o) {
    __shared__ unsigned short Kl[64][72];     // K tile [kv][d]
    __shared__ unsigned short Vl[64][72];     // V^T tile [d][kv]
    __shared__ unsigned short Pl[4][32][72];  // per-wave P [q 0..31][kv]
    const int tid = threadIdx.x;
    const int lane = tid & 63, wid = tid >> 6;
    const int lr = lane & 15, lg = lane >> 4;
    const int bh = blockIdx.y;
    const int qw = blockIdx.x * 128 + wid * 32;     // this wave's first q row
    const size_t base = (size_t)bh * NS * ND;       // same stride for q/k and vtt

    // Q fragments (B-operand: col = q = lane&15, k = d = lg*8 + j)
    short8 qfA0, qfA1, qfB0, qfB1;
    {
        const unsigned short* qp = q + base + (size_t)(qw + lr) * ND + lg * 8;
        qfA0 = *(const short8*)(qp);
        qfA1 = *(const short8*)(qp + 32);
        qfB0 = *(const short8*)(qp + 16 * ND);
        qfB1 = *(const short8*)(qp + 16 * ND + 32);
    }

    float mA = -__builtin_inff(), lA = 0.f, mB = -__builtin_inff(), lB = 0.f;
    f32x4 oaA[4], oaB[4];
#pragma unroll
    for (int n = 0; n < 4; ++n) { oaA[n] = (f32x4){0.f,0.f,0.f,0.f}; oaB[n] = (f32x4){0.f,0.f,0.f,0.f}; }

    // staging: 8KB tile / 256 threads = 32B (16 elems) per thread, contiguous
    const int strow = tid >> 2, stcol = (tid & 3) * 16;

    for (int kv0 = 0; kv0 < NS; kv0 += 64) {
        __syncthreads();
        {
            const unsigned short* ks = k   + base + (size_t)kv0 * ND + tid * 16;
            const unsigned short* vs = vtt + base + (size_t)kv0 * ND + tid * 16;
            short8 k0v = *(const short8*)(ks);
            short8 k1v = *(const short8*)(ks + 8);
            short8 v0v = *(const short8*)(vs);
            short8 v1v = *(const short8*)(vs + 8);
            *(short8*)&Kl[strow][stcol]     = k0v;
            *(short8*)&Kl[strow][stcol + 8] = k1v;
            *(short8*)&Vl[strow][stcol]     = v0v;
            *(short8*)&Vl[strow][stcol + 8] = v1v;
        }
        __syncthreads();

        // S^T = K·Q^T for both q-halves
        f32x4 stA[4], stB[4];
#pragma unroll
        for (int t = 0; t < 4; ++t) { stA[t] = (f32x4){0.f,0.f,0.f,0.f}; stB[t] = (f32x4){0.f,0.f,0.f,0.f}; }
#pragma unroll
        for (int t = 0; t < 4; ++t) {
            short8 kf0 = *(const short8*)&Kl[t * 16 + lr][lg * 8];
            short8 kf1 = *(const short8*)&Kl[t * 16 + lr][32 + lg * 8];
            stA[t] = __builtin_amdgcn_mfma_f32_16x16x32_bf16(kf0, qfA0, stA[t], 0, 0, 0);
            stA[t] = __builtin_amdgcn_mfma_f32_16x16x32_bf16(kf1, qfA1, stA[t], 0, 0, 0);
            stB[t] = __builtin_amdgcn_mfma_f32_16x16x32_bf16(kf0, qfB0, stB[t], 0, 0, 0);
            stB[t] = __builtin_amdgcn_mfma_f32_16x16x32_bf16(kf1, qfB1, stB[t], 0, 0, 0);
        }

        online_sm(stA, mA, lA, oaA);
        online_sm(stB, mB, lB, oaB);

        // P -> per-wave LDS (packed 8B writes), then A-fragment reads
#pragma unroll
        for (int t = 0; t < 4; ++t) {
            us4 pkA, pkB;
#pragma unroll
            for (int i = 0; i < 4; ++i) { pkA[i] = f2bf(stA[t][i]); pkB[i] = f2bf(stB[t][i]); }
            *(us4*)&Pl[wid][lr][t * 16 + lg * 4]      = pkA;
            *(us4*)&Pl[wid][16 + lr][t * 16 + lg * 4] = pkB;
        }
        short8 pfA0 = *(const short8*)&Pl[wid][lr][lg * 8];
        short8 pfA1 = *(const short8*)&Pl[wid][lr][32 + lg * 8];
        short8 pfB0 = *(const short8*)&Pl[wid][16 + lr][lg * 8];
        short8 pfB1 = *(const short8*)&Pl[wid][16 + lr][32 + lg * 8];

        // O^T += V^T · P^T
#pragma unroll
        for (int n = 0; n < 4; ++n) {
            short8 vf0 = *(const short8*)&Vl[n * 16 + lr][lg * 8];
            short8 vf1 = *(const short8*)&Vl[n * 16 + lr][32 + lg * 8];
            oaA[n] = __builtin_amdgcn_mfma_f32_16x16x32_bf16(vf0, pfA0, oaA[n], 0, 0, 0);
            oaA[n] = __builtin_amdgcn_mfma_f32_16x16x32_bf16(vf1, pfA1, oaA[n], 0, 0, 0);
            oaB[n] = __builtin_amdgcn_mfma_f32_16x16x32_bf16(vf0, pfB0, oaB[n], 0, 0, 0);
            oaB[n] = __builtin_amdgcn_mfma_f32_16x16x32_bf16(vf1, pfB1, oaB[n], 0, 0, 0);
        }
    }

    const int b = bh >> 4, h = bh & 15;
    const float sclA = 0.125f / lA;   // softmax BEFORE scaling -> /8 here
    const float sclB = 0.125f / lB;
    const int sA = qw + lr, sB = qw + 16 + lr;
#pragma unroll
    for (int n = 0; n < 4; ++n) {
        us4 pkA, pkB;
#pragma unroll
        for (int i = 0; i < 4; ++i) { pkA[i] = f2bf(oaA[n][i] * sclA); pkB[i] = f2bf(oaB[n][i] * sclB); }
        *(us4*)&o[(((size_t)b * NS + sA) * NH + h) * ND + n * 16 + lg * 4] = pkA;
        *(us4*)&o[(((size_t)b * NS + sB) * NH + h) * ND + n * 16 + lg * 4] = pkB;
    }
}

extern "C" void kernel_launch(void* const* d_in, const int* in_sizes, int n_in,
                              void* d_out, int out_size, void* d_ws, size_t ws_size,
                              hipStream_t stream) {
    (void)in_sizes; (void)n_in; (void)out_size; (void)ws_size;
    const float* values  = (const float*)d_in[0];
    const float* keys    = (const float*)d_in[1];
    const float* queries = (const float*)d_in[2];
    const float* Wv = (const float*)d_in[3];
    const float* Wk = (const float*)d_in[4];
    const float* Wq = (const float*)d_in[5];
    const float* Wo = (const float*)d_in[6];
    const float* bo = (const float*)d_in[7];

    uint8_t* ws = (uint8_t*)d_ws;
    const size_t MB = (size_t)1 << 20;
    unsigned short* wvb = (unsigned short*)(ws + 0 * MB);
    unsigned short* wkb = (unsigned short*)(ws + 2 * MB);
    unsigned short* wqb = (unsigned short*)(ws + 4 * MB);
    unsigned short* wob = (unsigned short*)(ws + 6 * MB);
    unsigned short* qb  = (unsigned short*)(ws + 8 * MB);   // [B,H,S,D] bf16, 16 MB
    unsigned short* kb  = (unsigned short*)(ws + 24 * MB);  // [B,H,S,D] bf16
    unsigned short* vtb = (unsigned short*)(ws + 40 * MB);  // [B,H,S/64,D,64] bf16 (V^T kv-blocked)
    unsigned short* ab  = (unsigned short*)(ws + 56 * MB);  // [B,S,H,D] bf16, 16 MB

    cvt_w_kernel<<<1024, 256, 0, stream>>>(Wv, wvb);
    cvt_w_kernel<<<1024, 256, 0, stream>>>(Wk, wkb);
    cvt_w_kernel<<<1024, 256, 0, stream>>>(Wq, wqb);

    dim3 gg(64, 8);  // (M/128, N/128)
    gemm_bt<1, 0><<<gg, 256, 0, stream>>>(queries, wqb, qb,  nullptr);
    gemm_bt<1, 0><<<gg, 256, 0, stream>>>(keys,    wkb, kb,  nullptr);
    gemm_bt<1, 2><<<gg, 256, 0, stream>>>(values,  wvb, vtb, nullptr);

    cvt_w_kernel<<<1024, 256, 0, stream>>>(Wo, wob);

    attn_kernel<<<dim3(16, 64), 256, 0, stream>>>(qb, kb, vtb, ab);

    gemm_bt<0, 1><<<gg, 256, 0, stream>>>(ab, wob, d_out, bo);
}

// Round 7
// 265.562 us; speedup vs baseline: 2.3293x; 1.2375x over previous
//
#include <hip/hip_runtime.h>
#include <stdint.h>

#define NB 4
#define NS 2048
#define NE 1024
#define NH 16
#define ND 64

typedef __attribute__((ext_vector_type(8))) short short8;
typedef __attribute__((ext_vector_type(4))) float f32x4;
typedef __attribute__((ext_vector_type(4))) unsigned short us4;

__device__ __forceinline__ unsigned short f2bf(float f) {
    unsigned u = __builtin_bit_cast(unsigned, f);
    u += 0x7FFFu + ((u >> 16) & 1u);   // round-to-nearest-even
    return (unsigned short)(u >> 16);
}

// ---------------- 4 weight matrices fp32 -> bf16, one launch ----------------
__global__ __launch_bounds__(256) void cvt_w4_kernel(const float* __restrict__ w0,
                                                     const float* __restrict__ w1,
                                                     const float* __restrict__ w2,
                                                     const float* __restrict__ w3,
                                                     unsigned short* __restrict__ d0,
                                                     unsigned short* __restrict__ d1,
                                                     unsigned short* __restrict__ d2,
                                                     unsigned short* __restrict__ d3) {
    const int g = blockIdx.x >> 10;            // which weight (1024 blocks each)
    const float* src = g == 0 ? w0 : g == 1 ? w1 : g == 2 ? w2 : w3;
    unsigned short* dst = g == 0 ? d0 : g == 1 ? d1 : g == 2 ? d2 : d3;
    const int i = ((blockIdx.x & 1023) * 256 + threadIdx.x) * 4;
    f32x4 f = *(const f32x4*)(src + i);
    us4 o;
#pragma unroll
    for (int j = 0; j < 4; ++j) o[j] = f2bf(f[j]);
    *(us4*)(dst + i) = o;
}

// ---------------- GEMM: C[M,N] = A[M,K] @ W[N,K]^T ----------------
// M=8192, N=1024, K=1024. 128x128 tile, BK=32, 4 waves (each 64x64).
// Reg-prefetch (T14): next BK-chunk loads issued in the compute shadow.
// A_IS_F32: A is fp32 (converted to bf16 during LDS write), else bf16.
// OUT_MODE 0: bf16 [B,H,S,D]. OUT_MODE 1: fp32 [M,N]+bias.
// OUT_MODE 2: bf16 V^T kv-blocked [B,H,S/64,D,64].
template<int A_IS_F32, int OUT_MODE>
__global__ __launch_bounds__(256) void gemm_bt(const void* __restrict__ Aptr,
                                               const unsigned short* __restrict__ Wp,
                                               void* __restrict__ Cp,
                                               const float* __restrict__ bias) {
    constexpr int K = 1024;
    __shared__ unsigned short As[128][40];  // pad 32->40: 2-way (free) bank pattern
    __shared__ unsigned short Bs[128][40];
    const int tid = threadIdx.x;
    const int bm = blockIdx.x, bn = blockIdx.y;
    const int lane = tid & 63, wid = tid >> 6;
    const int lr = lane & 15, lg = lane >> 4;
    const int wr = wid >> 1, wc = wid & 1;
    const int srow = tid >> 1, shalf = tid & 1;

    f32x4 acc[4][4];
#pragma unroll
    for (int a = 0; a < 4; ++a)
#pragma unroll
        for (int b = 0; b < 4; ++b) acc[a][b] = (f32x4){0.f, 0.f, 0.f, 0.f};

    const size_t arow = (size_t)(bm * 128 + srow) * K + shalf * 16;
    const size_t brow = (size_t)(bn * 128 + srow) * K + shalf * 16;
    const float*          apF = (const float*)Aptr + arow;
    const unsigned short* apH = (const unsigned short*)Aptr + arow;
    const unsigned short* bp  = Wp + brow;

    // prefetch registers (prologue: chunk k0=0)
    f32x4 pa0, pa1, pa2, pa3;
    short8 pah0, pah1, pb0, pb1;
    if (A_IS_F32) {
        pa0 = *(const f32x4*)(apF);
        pa1 = *(const f32x4*)(apF + 4);
        pa2 = *(const f32x4*)(apF + 8);
        pa3 = *(const f32x4*)(apF + 12);
    } else {
        pah0 = *(const short8*)(apH);
        pah1 = *(const short8*)(apH + 8);
    }
    pb0 = *(const short8*)(bp);
    pb1 = *(const short8*)(bp + 8);

    for (int k0 = 0; k0 < K; k0 += 32) {
        __syncthreads();  // all waves done reading previous LDS contents
        if (A_IS_F32) {
            short8 p0, p1;
#pragma unroll
            for (int j = 0; j < 4; ++j) {
                p0[j]     = (short)f2bf(pa0[j]);
                p0[j + 4] = (short)f2bf(pa1[j]);
                p1[j]     = (short)f2bf(pa2[j]);
                p1[j + 4] = (short)f2bf(pa3[j]);
            }
            *(short8*)&As[srow][shalf * 16]     = p0;
            *(short8*)&As[srow][shalf * 16 + 8] = p1;
        } else {
            *(short8*)&As[srow][shalf * 16]     = pah0;
            *(short8*)&As[srow][shalf * 16 + 8] = pah1;
        }
        *(short8*)&Bs[srow][shalf * 16]     = pb0;
        *(short8*)&Bs[srow][shalf * 16 + 8] = pb1;
        __syncthreads();

        // issue next chunk's loads; they fly under the MFMA section below
        if (k0 + 32 < K) {
            const int kn = k0 + 32;
            if (A_IS_F32) {
                pa0 = *(const f32x4*)(apF + kn);
                pa1 = *(const f32x4*)(apF + kn + 4);
                pa2 = *(const f32x4*)(apF + kn + 8);
                pa3 = *(const f32x4*)(apF + kn + 12);
            } else {
                pah0 = *(const short8*)(apH + kn);
                pah1 = *(const short8*)(apH + kn + 8);
            }
            pb0 = *(const short8*)(bp + kn);
            pb1 = *(const short8*)(bp + kn + 8);
        }

        short8 af[4], bfr[4];
#pragma unroll
        for (int mi = 0; mi < 4; ++mi) af[mi]  = *(const short8*)&As[wr * 64 + mi * 16 + lr][lg * 8];
#pragma unroll
        for (int ni = 0; ni < 4; ++ni) bfr[ni] = *(const short8*)&Bs[wc * 64 + ni * 16 + lr][lg * 8];
#pragma unroll
        for (int mi = 0; mi < 4; ++mi)
#pragma unroll
            for (int ni = 0; ni < 4; ++ni)
                acc[mi][ni] = __builtin_amdgcn_mfma_f32_16x16x32_bf16(af[mi], bfr[ni], acc[mi][ni], 0, 0, 0);
    }

#pragma unroll
    for (int mi = 0; mi < 4; ++mi) {
#pragma unroll
        for (int ni = 0; ni < 4; ++ni) {
            const int n = bn * 128 + wc * 64 + ni * 16 + lr;
            if (OUT_MODE == 2) {
                // V^T kv-blocked: [B,H,S/64,D,64]; i -> s consecutive within a 64-block.
                const int m0 = bm * 128 + wr * 64 + mi * 16 + lg * 4;
                const int b = m0 >> 11, s0 = m0 & 2047;
                const int h = n >> 6, d = n & 63;
                us4 pk;
#pragma unroll
                for (int i = 0; i < 4; ++i) pk[i] = f2bf(acc[mi][ni][i]);
                const size_t idx = ((((size_t)b * NH + h) * (NS / 64) + (s0 >> 6)) * ND + d) * 64 + (s0 & 63);
                *(us4*)&((unsigned short*)Cp)[idx] = pk;
            } else {
#pragma unroll
                for (int i = 0; i < 4; ++i) {
                    const int m = bm * 128 + wr * 64 + mi * 16 + lg * 4 + i;
                    const float val = acc[mi][ni][i];
                    if (OUT_MODE == 0) {
                        const int b = m >> 11, s = m & 2047, h = n >> 6, d = n & 63;
                        ((unsigned short*)Cp)[(((size_t)b * NH + h) * NS + s) * ND + d] = f2bf(val);
                    } else {
                        ((float*)Cp)[(size_t)m * 1024 + n] = val + bias[n];
                    }
                }
            }
        }
    }
}

__device__ __forceinline__ void online_sm(f32x4 st[4], float& m_run, float& l_run, f32x4 oa[4]) {
    float pm = st[0][0];
#pragma unroll
    for (int t = 0; t < 4; ++t)
#pragma unroll
        for (int i = 0; i < 4; ++i) pm = fmaxf(pm, st[t][i]);
    pm = fmaxf(pm, __shfl_xor(pm, 16, 64));
    pm = fmaxf(pm, __shfl_xor(pm, 32, 64));
    const float mn = fmaxf(m_run, pm);
    const float alpha = __expf(m_run - mn);
    m_run = mn;
    float rs = 0.f;
#pragma unroll
    for (int t = 0; t < 4; ++t)
#pragma unroll
        for (int i = 0; i < 4; ++i) {
            float p = __expf(st[t][i] - mn);
            st[t][i] = p;
            rs += p;
        }
    rs += __shfl_xor(rs, 16, 64);
    rs += __shfl_xor(rs, 32, 64);
    l_run = l_run * alpha + rs;
#pragma unroll
    for (int n = 0; n < 4; ++n)
#pragma unroll
        for (int i = 0; i < 4; ++i) oa[n][i] *= alpha;
}

// ---------------- flash attention (swapped-operand, QBLK=32/wave, reg-prefetch) ----------------
// grid (S/128, B*H), 256 threads. Wave w owns q rows q0+w*32 .. +31 (2 fragments A/B).
// q,k layout: [B,H,S,D] bf16. vtt layout: [B,H,S/64,D,64] bf16 (V^T, kv-blocked).
// T14: next K/V tile is loaded into regs during the current tile's compute; the
// ds_write at the next iteration top absorbs the vmcnt wait after a full tile.
//   S^T = mfma(K_frag, Q_frag):    C col = q = lane&15, row = kv = 16t + (lane>>4)*4 + i
//   O^T = mfma(Vt_frag, P^T_frag): C col = q = lane&15, row = d  = 16n + (lane>>4)*4 + i
__global__ __launch_bounds__(256) void attn_kernel(const unsigned short* __restrict__ q,
                                                   const unsigned short* __restrict__ k,
                                                   const unsigned short* __restrict__ vtt,
                                                   unsigned short* __restrict__ o) {
    __shared__ unsigned short Kl[64][72];     // K tile [kv][d]
    __shared__ unsigned short Vl[64][72];     // V^T tile [d][kv]
    __shared__ unsigned short Pl[4][32][72];  // per-wave P [q 0..31][kv]
    const int tid = threadIdx.x;
    const int lane = tid & 63, wid = tid >> 6;
    const int lr = lane & 15, lg = lane >> 4;
    const int bh = blockIdx.y;
    const int qw = blockIdx.x * 128 + wid * 32;     // this wave's first q row
    const size_t base = (size_t)bh * NS * ND;       // same stride for q/k and vtt

    // Q fragments (B-operand: col = q = lane&15, k = d = lg*8 + j)
    short8 qfA0, qfA1, qfB0, qfB1;
    {
        const unsigned short* qp = q + base + (size_t)(qw + lr) * ND + lg * 8;
        qfA0 = *(const short8*)(qp);
        qfA1 = *(const short8*)(qp + 32);
        qfB0 = *(const short8*)(qp + 16 * ND);
        qfB1 = *(const short8*)(qp + 16 * ND + 32);
    }

    float mA = -__builtin_inff(), lA = 0.f, mB = -__builtin_inff(), lB = 0.f;
    f32x4 oaA[4], oaB[4];
#pragma unroll
    for (int n = 0; n < 4; ++n) { oaA[n] = (f32x4){0.f,0.f,0.f,0.f}; oaB[n] = (f32x4){0.f,0.f,0.f,0.f}; }

    // staging: 8KB tile / 256 threads = 32B (16 elems) per thread, contiguous
    const int strow = tid >> 2, stcol = (tid & 3) * 16;
    const unsigned short* ks = k   + base + tid * 16;   // + kv0*ND per tile
    const unsigned short* vs = vtt + base + tid * 16;

    // prologue: prefetch tile kv0=0
    short8 kr0 = *(const short8*)(ks);
    short8 kr1 = *(const short8*)(ks + 8);
    short8 vr0 = *(const short8*)(vs);
    short8 vr1 = *(const short8*)(vs + 8);

    for (int kv0 = 0; kv0 < NS; kv0 += 64) {
        __syncthreads();                          // all waves done reading prev tile
        *(short8*)&Kl[strow][stcol]     = kr0;    // vmcnt wait lands here, after a full tile
        *(short8*)&Kl[strow][stcol + 8] = kr1;
        *(short8*)&Vl[strow][stcol]     = vr0;
        *(short8*)&Vl[strow][stcol + 8] = vr1;
        __syncthreads();

        // issue next tile's loads; they fly under this tile's compute
        if (kv0 + 64 < NS) {
            const unsigned short* ks2 = ks + (size_t)(kv0 + 64) * ND;
            const unsigned short* vs2 = vs + (size_t)(kv0 + 64) * ND;
            kr0 = *(const short8*)(ks2);
            kr1 = *(const short8*)(ks2 + 8);
            vr0 = *(const short8*)(vs2);
            vr1 = *(const short8*)(vs2 + 8);
        }

        // S^T = K·Q^T for both q-halves
        f32x4 stA[4], stB[4];
#pragma unroll
        for (int t = 0; t < 4; ++t) { stA[t] = (f32x4){0.f,0.f,0.f,0.f}; stB[t] = (f32x4){0.f,0.f,0.f,0.f}; }
        __builtin_amdgcn_s_setprio(1);
#pragma unroll
        for (int t = 0; t < 4; ++t) {
            short8 kf0 = *(const short8*)&Kl[t * 16 + lr][lg * 8];
            short8 kf1 = *(const short8*)&Kl[t * 16 + lr][32 + lg * 8];
            stA[t] = __builtin_amdgcn_mfma_f32_16x16x32_bf16(kf0, qfA0, stA[t], 0, 0, 0);
            stA[t] = __builtin_amdgcn_mfma_f32_16x16x32_bf16(kf1, qfA1, stA[t], 0, 0, 0);
            stB[t] = __builtin_amdgcn_mfma_f32_16x16x32_bf16(kf0, qfB0, stB[t], 0, 0, 0);
            stB[t] = __builtin_amdgcn_mfma_f32_16x16x32_bf16(kf1, qfB1, stB[t], 0, 0, 0);
        }
        __builtin_amdgcn_s_setprio(0);

        online_sm(stA, mA, lA, oaA);
        online_sm(stB, mB, lB, oaB);

        // P -> per-wave LDS (packed 8B writes), then A-fragment reads
#pragma unroll
        for (int t = 0; t < 4; ++t) {
            us4 pkA, pkB;
#pragma unroll
            for (int i = 0; i < 4; ++i) { pkA[i] = f2bf(stA[t][i]); pkB[i] = f2bf(stB[t][i]); }
            *(us4*)&Pl[wid][lr][t * 16 + lg * 4]      = pkA;
            *(us4*)&Pl[wid][16 + lr][t * 16 + lg * 4] = pkB;
        }
        short8 pfA0 = *(const short8*)&Pl[wid][lr][lg * 8];
        short8 pfA1 = *(const short8*)&Pl[wid][lr][32 + lg * 8];
        short8 pfB0 = *(const short8*)&Pl[wid][16 + lr][lg * 8];
        short8 pfB1 = *(const short8*)&Pl[wid][16 + lr][32 + lg * 8];

        // O^T += V^T · P^T
        __builtin_amdgcn_s_setprio(1);
#pragma unroll
        for (int n = 0; n < 4; ++n) {
            short8 vf0 = *(const short8*)&Vl[n * 16 + lr][lg * 8];
            short8 vf1 = *(const short8*)&Vl[n * 16 + lr][32 + lg * 8];
            oaA[n] = __builtin_amdgcn_mfma_f32_16x16x32_bf16(vf0, pfA0, oaA[n], 0, 0, 0);
            oaA[n] = __builtin_amdgcn_mfma_f32_16x16x32_bf16(vf1, pfA1, oaA[n], 0, 0, 0);
            oaB[n] = __builtin_amdgcn_mfma_f32_16x16x32_bf16(vf0, pfB0, oaB[n], 0, 0, 0);
            oaB[n] = __builtin_amdgcn_mfma_f32_16x16x32_bf16(vf1, pfB1, oaB[n], 0, 0, 0);
        }
        __builtin_amdgcn_s_setprio(0);
    }

    const int b = bh >> 4, h = bh & 15;
    const float sclA = 0.125f / lA;   // softmax BEFORE scaling -> /8 here
    const float sclB = 0.125f / lB;
    const int sA = qw + lr, sB = qw + 16 + lr;
#pragma unroll
    for (int n = 0; n < 4; ++n) {
        us4 pkA, pkB;
#pragma unroll
        for (int i = 0; i < 4; ++i) { pkA[i] = f2bf(oaA[n][i] * sclA); pkB[i] = f2bf(oaB[n][i] * sclB); }
        *(us4*)&o[(((size_t)b * NS + sA) * NH + h) * ND + n * 16 + lg * 4] = pkA;
        *(us4*)&o[(((size_t)b * NS + sB) * NH + h) * ND + n * 16 + lg * 4] = pkB;
    }
}

extern "C" void kernel_launch(void* const* d_in, const int* in_sizes, int n_in,
                              void* d_out, int out_size, void* d_ws, size_t ws_size,
                              hipStream_t stream) {
    (void)in_sizes; (void)n_in; (void)out_size; (void)ws_size;
    const float* values  = (const float*)d_in[0];
    const float* keys    = (const float*)d_in[1];
    const float* queries = (const float*)d_in[2];
    const float* Wv = (const float*)d_in[3];
    const float* Wk = (const float*)d_in[4];
    const float* Wq = (const float*)d_in[5];
    const float* Wo = (const float*)d_in[6];
    const float* bo = (const float*)d_in[7];

    uint8_t* ws = (uint8_t*)d_ws;
    const size_t MB = (size_t)1 << 20;
    unsigned short* wvb = (unsigned short*)(ws + 0 * MB);
    unsigned short* wkb = (unsigned short*)(ws + 2 * MB);
    unsigned short* wqb = (unsigned short*)(ws + 4 * MB);
    unsigned short* wob = (unsigned short*)(ws + 6 * MB);
    unsigned short* qb  = (unsigned short*)(ws + 8 * MB);   // [B,H,S,D] bf16, 16 MB
    unsigned short* kb  = (unsigned short*)(ws + 24 * MB);  // [B,H,S,D] bf16
    unsigned short* vtb = (unsigned short*)(ws + 40 * MB);  // [B,H,S/64,D,64] bf16 (V^T kv-blocked)
    unsigned short* ab  = (unsigned short*)(ws + 56 * MB);  // [B,S,H,D] bf16, 16 MB

    cvt_w4_kernel<<<4096, 256, 0, stream>>>(Wv, Wk, Wq, Wo, wvb, wkb, wqb, wob);

    dim3 gg(64, 8);  // (M/128, N/128)
    gemm_bt<1, 0><<<gg, 256, 0, stream>>>(queries, wqb, qb,  nullptr);
    gemm_bt<1, 0><<<gg, 256, 0, stream>>>(keys,    wkb, kb,  nullptr);
    gemm_bt<1, 2><<<gg, 256, 0, stream>>>(values,  wvb, vtb, nullptr);

    attn_kernel<<<dim3(16, 64), 256, 0, stream>>>(qb, kb, vtb, ab);

    gemm_bt<0, 1><<<gg, 256, 0, stream>>>(ab, wob, d_out, bo);
}

// Round 8
// 258.246 us; speedup vs baseline: 2.3953x; 1.0283x over previous
//
#include <hip/hip_runtime.h>
#include <stdint.h>

#define NB 4
#define NS 2048
#define NE 1024
#define NH 16
#define ND 64

typedef __attribute__((ext_vector_type(8))) short short8;
typedef __attribute__((ext_vector_type(4))) float f32x4;
typedef __attribute__((ext_vector_type(4))) unsigned short us4;

// f32 -> bf16 RNE via native cast: clang emits v_cvt_pk_bf16_f32 pairs on gfx950
// (bit-identical to the manual round-to-nearest-even bit hack for non-NaN input).
__device__ __forceinline__ unsigned short f2bf(float f) {
    return __builtin_bit_cast(unsigned short, static_cast<__bf16>(f));
}

// ---------------- 4 weight matrices fp32 -> bf16, one launch ----------------
__global__ __launch_bounds__(256) void cvt_w4_kernel(const float* __restrict__ w0,
                                                     const float* __restrict__ w1,
                                                     const float* __restrict__ w2,
                                                     const float* __restrict__ w3,
                                                     unsigned short* __restrict__ d0,
                                                     unsigned short* __restrict__ d1,
                                                     unsigned short* __restrict__ d2,
                                                     unsigned short* __restrict__ d3) {
    const int g = blockIdx.x >> 10;            // which weight (1024 blocks each)
    const float* src = g == 0 ? w0 : g == 1 ? w1 : g == 2 ? w2 : w3;
    unsigned short* dst = g == 0 ? d0 : g == 1 ? d1 : g == 2 ? d2 : d3;
    const int i = ((blockIdx.x & 1023) * 256 + threadIdx.x) * 4;
    f32x4 f = *(const f32x4*)(src + i);
    us4 o;
#pragma unroll
    for (int j = 0; j < 4; ++j) o[j] = f2bf(f[j]);
    *(us4*)(dst + i) = o;
}

// ---------------- GEMM: C[M,N] = A[M,K] @ W[N,K]^T ----------------
// M=8192, N=1024, K=1024. 128x128 tile, BK=32, 4 waves (each 64x64).
// Reg-prefetch (T14): next BK-chunk loads issued in the compute shadow.
// A_IS_F32: A is fp32 (converted to bf16 during LDS write), else bf16.
// OUT_MODE 0: bf16 [B,H,S,D]. OUT_MODE 1: fp32 [M,N]+bias.
// OUT_MODE 2: bf16 V^T kv-blocked [B,H,S/64,D,64].
template<int A_IS_F32, int OUT_MODE>
__global__ __launch_bounds__(256) void gemm_bt(const void* __restrict__ Aptr,
                                               const unsigned short* __restrict__ Wp,
                                               void* __restrict__ Cp,
                                               const float* __restrict__ bias) {
    constexpr int K = 1024;
    __shared__ unsigned short As[128][40];  // pad 32->40: 2-way (free) bank pattern
    __shared__ unsigned short Bs[128][40];
    const int tid = threadIdx.x;
    const int bm = blockIdx.x, bn = blockIdx.y;
    const int lane = tid & 63, wid = tid >> 6;
    const int lr = lane & 15, lg = lane >> 4;
    const int wr = wid >> 1, wc = wid & 1;
    const int srow = tid >> 1, shalf = tid & 1;

    f32x4 acc[4][4];
#pragma unroll
    for (int a = 0; a < 4; ++a)
#pragma unroll
        for (int b = 0; b < 4; ++b) acc[a][b] = (f32x4){0.f, 0.f, 0.f, 0.f};

    const size_t arow = (size_t)(bm * 128 + srow) * K + shalf * 16;
    const size_t brow = (size_t)(bn * 128 + srow) * K + shalf * 16;
    const float*          apF = (const float*)Aptr + arow;
    const unsigned short* apH = (const unsigned short*)Aptr + arow;
    const unsigned short* bp  = Wp + brow;

    // prefetch registers (prologue: chunk k0=0)
    f32x4 pa0, pa1, pa2, pa3;
    short8 pah0, pah1, pb0, pb1;
    if (A_IS_F32) {
        pa0 = *(const f32x4*)(apF);
        pa1 = *(const f32x4*)(apF + 4);
        pa2 = *(const f32x4*)(apF + 8);
        pa3 = *(const f32x4*)(apF + 12);
    } else {
        pah0 = *(const short8*)(apH);
        pah1 = *(const short8*)(apH + 8);
    }
    pb0 = *(const short8*)(bp);
    pb1 = *(const short8*)(bp + 8);

    for (int k0 = 0; k0 < K; k0 += 32) {
        __syncthreads();  // all waves done reading previous LDS contents
        if (A_IS_F32) {
            short8 p0, p1;
#pragma unroll
            for (int j = 0; j < 4; ++j) {
                p0[j]     = (short)f2bf(pa0[j]);
                p0[j + 4] = (short)f2bf(pa1[j]);
                p1[j]     = (short)f2bf(pa2[j]);
                p1[j + 4] = (short)f2bf(pa3[j]);
            }
            *(short8*)&As[srow][shalf * 16]     = p0;
            *(short8*)&As[srow][shalf * 16 + 8] = p1;
        } else {
            *(short8*)&As[srow][shalf * 16]     = pah0;
            *(short8*)&As[srow][shalf * 16 + 8] = pah1;
        }
        *(short8*)&Bs[srow][shalf * 16]     = pb0;
        *(short8*)&Bs[srow][shalf * 16 + 8] = pb1;
        __syncthreads();

        // issue next chunk's loads; they fly under the MFMA section below
        if (k0 + 32 < K) {
            const int kn = k0 + 32;
            if (A_IS_F32) {
                pa0 = *(const f32x4*)(apF + kn);
                pa1 = *(const f32x4*)(apF + kn + 4);
                pa2 = *(const f32x4*)(apF + kn + 8);
                pa3 = *(const f32x4*)(apF + kn + 12);
            } else {
                pah0 = *(const short8*)(apH + kn);
                pah1 = *(const short8*)(apH + kn + 8);
            }
            pb0 = *(const short8*)(bp + kn);
            pb1 = *(const short8*)(bp + kn + 8);
        }

        short8 af[4], bfr[4];
#pragma unroll
        for (int mi = 0; mi < 4; ++mi) af[mi]  = *(const short8*)&As[wr * 64 + mi * 16 + lr][lg * 8];
#pragma unroll
        for (int ni = 0; ni < 4; ++ni) bfr[ni] = *(const short8*)&Bs[wc * 64 + ni * 16 + lr][lg * 8];
#pragma unroll
        for (int mi = 0; mi < 4; ++mi)
#pragma unroll
            for (int ni = 0; ni < 4; ++ni)
                acc[mi][ni] = __builtin_amdgcn_mfma_f32_16x16x32_bf16(af[mi], bfr[ni], acc[mi][ni], 0, 0, 0);
    }

#pragma unroll
    for (int mi = 0; mi < 4; ++mi) {
#pragma unroll
        for (int ni = 0; ni < 4; ++ni) {
            const int n = bn * 128 + wc * 64 + ni * 16 + lr;
            if (OUT_MODE == 2) {
                // V^T kv-blocked: [B,H,S/64,D,64]; i -> s consecutive within a 64-block.
                const int m0 = bm * 128 + wr * 64 + mi * 16 + lg * 4;
                const int b = m0 >> 11, s0 = m0 & 2047;
                const int h = n >> 6, d = n & 63;
                us4 pk;
#pragma unroll
                for (int i = 0; i < 4; ++i) pk[i] = f2bf(acc[mi][ni][i]);
                const size_t idx = ((((size_t)b * NH + h) * (NS / 64) + (s0 >> 6)) * ND + d) * 64 + (s0 & 63);
                *(us4*)&((unsigned short*)Cp)[idx] = pk;
            } else {
#pragma unroll
                for (int i = 0; i < 4; ++i) {
                    const int m = bm * 128 + wr * 64 + mi * 16 + lg * 4 + i;
                    const float val = acc[mi][ni][i];
                    if (OUT_MODE == 0) {
                        const int b = m >> 11, s = m & 2047, h = n >> 6, d = n & 63;
                        ((unsigned short*)Cp)[(((size_t)b * NH + h) * NS + s) * ND + d] = f2bf(val);
                    } else {
                        ((float*)Cp)[(size_t)m * 1024 + n] = val + bias[n];
                    }
                }
            }
        }
    }
}

// Online softmax with T13(THR=0): the rescale branch is taken only when some
// q-row's max grew; in the skip case the old code multiplied by exactly 1.0,
// so skipping is bit-identical.
__device__ __forceinline__ void online_sm(f32x4 st[4], float& m_run, float& l_run, f32x4 oa[4]) {
    float pm = st[0][0];
#pragma unroll
    for (int t = 0; t < 4; ++t)
#pragma unroll
        for (int i = 0; i < 4; ++i) pm = fmaxf(pm, st[t][i]);
    pm = fmaxf(pm, __shfl_xor(pm, 16, 64));
    pm = fmaxf(pm, __shfl_xor(pm, 32, 64));
    if (!__all(pm <= m_run)) {
        const float mn = fmaxf(m_run, pm);
        const float alpha = __expf(m_run - mn);
        m_run = mn;
        l_run *= alpha;
#pragma unroll
        for (int n = 0; n < 4; ++n)
#pragma unroll
            for (int i = 0; i < 4; ++i) oa[n][i] *= alpha;
    }
    float rs = 0.f;
#pragma unroll
    for (int t = 0; t < 4; ++t)
#pragma unroll
        for (int i = 0; i < 4; ++i) {
            float p = __expf(st[t][i] - m_run);
            st[t][i] = p;
            rs += p;
        }
    rs += __shfl_xor(rs, 16, 64);
    rs += __shfl_xor(rs, 32, 64);
    l_run += rs;
}

// ---------------- flash attention (swapped-operand, QBLK=32/wave, reg-prefetch) ----------------
// grid (S/128, B*H), 256 threads. Wave w owns q rows q0+w*32 .. +31 (2 fragments A/B).
// q,k layout: [B,H,S,D] bf16. vtt layout: [B,H,S/64,D,64] bf16 (V^T, kv-blocked).
// T14: next K/V tile is loaded into regs during the current tile's compute.
//   S^T = mfma(K_frag, Q_frag):    C col = q = lane&15, row = kv = 16t + (lane>>4)*4 + i
//   O^T = mfma(Vt_frag, P^T_frag): C col = q = lane&15, row = d  = 16n + (lane>>4)*4 + i
__global__ __launch_bounds__(256) void attn_kernel(const unsigned short* __restrict__ q,
                                                   const unsigned short* __restrict__ k,
                                                   const unsigned short* __restrict__ vtt,
                                                   unsigned short* __restrict__ o) {
    __shared__ unsigned short Kl[64][72];     // K tile [kv][d]
    __shared__ unsigned short Vl[64][72];     // V^T tile [d][kv]
    __shared__ unsigned short Pl[4][32][72];  // per-wave P [q 0..31][kv]
    const int tid = threadIdx.x;
    const int lane = tid & 63, wid = tid >> 6;
    const int lr = lane & 15, lg = lane >> 4;
    const int bh = blockIdx.y;
    const int qw = blockIdx.x * 128 + wid * 32;     // this wave's first q row
    const size_t base = (size_t)bh * NS * ND;       // same stride for q/k and vtt

    // Q fragments (B-operand: col = q = lane&15, k = d = lg*8 + j)
    short8 qfA0, qfA1, qfB0, qfB1;
    {
        const unsigned short* qp = q + base + (size_t)(qw + lr) * ND + lg * 8;
        qfA0 = *(const short8*)(qp);
        qfA1 = *(const short8*)(qp + 32);
        qfB0 = *(const short8*)(qp + 16 * ND);
        qfB1 = *(const short8*)(qp + 16 * ND + 32);
    }

    float mA = -__builtin_inff(), lA = 0.f, mB = -__builtin_inff(), lB = 0.f;
    f32x4 oaA[4], oaB[4];
#pragma unroll
    for (int n = 0; n < 4; ++n) { oaA[n] = (f32x4){0.f,0.f,0.f,0.f}; oaB[n] = (f32x4){0.f,0.f,0.f,0.f}; }
    const f32x4 fz = (f32x4){0.f, 0.f, 0.f, 0.f};   // persistent zero C-operand

    // staging: 8KB tile / 256 threads = 32B (16 elems) per thread, contiguous
    const int strow = tid >> 2, stcol = (tid & 3) * 16;
    const unsigned short* ks = k   + base + tid * 16;   // + kv0*ND per tile
    const unsigned short* vs = vtt + base + tid * 16;

    // prologue: prefetch tile kv0=0
    short8 kr0 = *(const short8*)(ks);
    short8 kr1 = *(const short8*)(ks + 8);
    short8 vr0 = *(const short8*)(vs);
    short8 vr1 = *(const short8*)(vs + 8);

    for (int kv0 = 0; kv0 < NS; kv0 += 64) {
        __syncthreads();                          // all waves done reading prev tile
        *(short8*)&Kl[strow][stcol]     = kr0;    // vmcnt wait lands here, after a full tile
        *(short8*)&Kl[strow][stcol + 8] = kr1;
        *(short8*)&Vl[strow][stcol]     = vr0;
        *(short8*)&Vl[strow][stcol + 8] = vr1;
        __syncthreads();

        // issue next tile's loads; they fly under this tile's compute
        if (kv0 + 64 < NS) {
            const unsigned short* ks2 = ks + (size_t)(kv0 + 64) * ND;
            const unsigned short* vs2 = vs + (size_t)(kv0 + 64) * ND;
            kr0 = *(const short8*)(ks2);
            kr1 = *(const short8*)(ks2 + 8);
            vr0 = *(const short8*)(vs2);
            vr1 = *(const short8*)(vs2 + 8);
        }

        // S^T = K·Q^T for both q-halves (first MFMA consumes the zero C-operand)
        f32x4 stA[4], stB[4];
        __builtin_amdgcn_s_setprio(1);
#pragma unroll
        for (int t = 0; t < 4; ++t) {
            short8 kf0 = *(const short8*)&Kl[t * 16 + lr][lg * 8];
            short8 kf1 = *(const short8*)&Kl[t * 16 + lr][32 + lg * 8];
            stA[t] = __builtin_amdgcn_mfma_f32_16x16x32_bf16(kf0, qfA0, fz, 0, 0, 0);
            stA[t] = __builtin_amdgcn_mfma_f32_16x16x32_bf16(kf1, qfA1, stA[t], 0, 0, 0);
            stB[t] = __builtin_amdgcn_mfma_f32_16x16x32_bf16(kf0, qfB0, fz, 0, 0, 0);
            stB[t] = __builtin_amdgcn_mfma_f32_16x16x32_bf16(kf1, qfB1, stB[t], 0, 0, 0);
        }
        __builtin_amdgcn_s_setprio(0);

        online_sm(stA, mA, lA, oaA);
        online_sm(stB, mB, lB, oaB);

        // P -> per-wave LDS (packed 8B writes), then A-fragment reads
#pragma unroll
        for (int t = 0; t < 4; ++t) {
            us4 pkA, pkB;
#pragma unroll
            for (int i = 0; i < 4; ++i) { pkA[i] = f2bf(stA[t][i]); pkB[i] = f2bf(stB[t][i]); }
            *(us4*)&Pl[wid][lr][t * 16 + lg * 4]      = pkA;
            *(us4*)&Pl[wid][16 + lr][t * 16 + lg * 4] = pkB;
        }
        short8 pfA0 = *(const short8*)&Pl[wid][lr][lg * 8];
        short8 pfA1 = *(const short8*)&Pl[wid][lr][32 + lg * 8];
        short8 pfB0 = *(const short8*)&Pl[wid][16 + lr][lg * 8];
        short8 pfB1 = *(const short8*)&Pl[wid][16 + lr][32 + lg * 8];

        // O^T += V^T · P^T
        __builtin_amdgcn_s_setprio(1);
#pragma unroll
        for (int n = 0; n < 4; ++n) {
            short8 vf0 = *(const short8*)&Vl[n * 16 + lr][lg * 8];
            short8 vf1 = *(const short8*)&Vl[n * 16 + lr][32 + lg * 8];
            oaA[n] = __builtin_amdgcn_mfma_f32_16x16x32_bf16(vf0, pfA0, oaA[n], 0, 0, 0);
            oaA[n] = __builtin_amdgcn_mfma_f32_16x16x32_bf16(vf1, pfA1, oaA[n], 0, 0, 0);
            oaB[n] = __builtin_amdgcn_mfma_f32_16x16x32_bf16(vf0, pfB0, oaB[n], 0, 0, 0);
            oaB[n] = __builtin_amdgcn_mfma_f32_16x16x32_bf16(vf1, pfB1, oaB[n], 0, 0, 0);
        }
        __builtin_amdgcn_s_setprio(0);
    }

    const int b = bh >> 4, h = bh & 15;
    const float sclA = 0.125f / lA;   // softmax BEFORE scaling -> /8 here
    const float sclB = 0.125f / lB;
    const int sA = qw + lr, sB = qw + 16 + lr;
#pragma unroll
    for (int n = 0; n < 4; ++n) {
        us4 pkA, pkB;
#pragma unroll
        for (int i = 0; i < 4; ++i) { pkA[i] = f2bf(oaA[n][i] * sclA); pkB[i] = f2bf(oaB[n][i] * sclB); }
        *(us4*)&o[(((size_t)b * NS + sA) * NH + h) * ND + n * 16 + lg * 4] = pkA;
        *(us4*)&o[(((size_t)b * NS + sB) * NH + h) * ND + n * 16 + lg * 4] = pkB;
    }
}

extern "C" void kernel_launch(void* const* d_in, const int* in_sizes, int n_in,
                              void* d_out, int out_size, void* d_ws, size_t ws_size,
                              hipStream_t stream) {
    (void)in_sizes; (void)n_in; (void)out_size; (void)ws_size;
    const float* values  = (const float*)d_in[0];
    const float* keys    = (const float*)d_in[1];
    const float* queries = (const float*)d_in[2];
    const float* Wv = (const float*)d_in[3];
    const float* Wk = (const float*)d_in[4];
    const float* Wq = (const float*)d_in[5];
    const float* Wo = (const float*)d_in[6];
    const float* bo = (const float*)d_in[7];

    uint8_t* ws = (uint8_t*)d_ws;
    const size_t MB = (size_t)1 << 20;
    unsigned short* wvb = (unsigned short*)(ws + 0 * MB);
    unsigned short* wkb = (unsigned short*)(ws + 2 * MB);
    unsigned short* wqb = (unsigned short*)(ws + 4 * MB);
    unsigned short* wob = (unsigned short*)(ws + 6 * MB);
    unsigned short* qb  = (unsigned short*)(ws + 8 * MB);   // [B,H,S,D] bf16, 16 MB
    unsigned short* kb  = (unsigned short*)(ws + 24 * MB);  // [B,H,S,D] bf16
    unsigned short* vtb = (unsigned short*)(ws + 40 * MB);  // [B,H,S/64,D,64] bf16 (V^T kv-blocked)
    unsigned short* ab  = (unsigned short*)(ws + 56 * MB);  // [B,S,H,D] bf16, 16 MB

    cvt_w4_kernel<<<4096, 256, 0, stream>>>(Wv, Wk, Wq, Wo, wvb, wkb, wqb, wob);

    dim3 gg(64, 8);  // (M/128, N/128)
    gemm_bt<1, 0><<<gg, 256, 0, stream>>>(queries, wqb, qb,  nullptr);
    gemm_bt<1, 0><<<gg, 256, 0, stream>>>(keys,    wkb, kb,  nullptr);
    gemm_bt<1, 2><<<gg, 256, 0, stream>>>(values,  wvb, vtb, nullptr);

    attn_kernel<<<dim3(16, 64), 256, 0, stream>>>(qb, kb, vtb, ab);

    gemm_bt<0, 1><<<gg, 256, 0, stream>>>(ab, wob, d_out, bo);
}

// Round 9
// 245.547 us; speedup vs baseline: 2.5192x; 1.0517x over previous
//
#include <hip/hip_runtime.h>
#include <stdint.h>

#define NB 4
#define NS 2048
#define NE 1024
#define NH 16
#define ND 64

typedef __attribute__((ext_vector_type(8))) short short8;
typedef __attribute__((ext_vector_type(4))) float f32x4;
typedef __attribute__((ext_vector_type(16))) float f32x16;
typedef __attribute__((ext_vector_type(4))) unsigned short us4;
typedef __attribute__((ext_vector_type(4))) unsigned int u32x4;

// f32 -> bf16 RNE via native cast (clang emits v_cvt_pk_bf16_f32 pairs).
__device__ __forceinline__ unsigned short f2bf(float f) {
    return __builtin_bit_cast(unsigned short, static_cast<__bf16>(f));
}
__device__ __forceinline__ unsigned int packbf(float lo, float hi_) {
    return (unsigned int)f2bf(lo) | ((unsigned int)f2bf(hi_) << 16);
}

// ---------------- 4 weight matrices fp32 -> bf16, one launch ----------------
__global__ __launch_bounds__(256) void cvt_w4_kernel(const float* __restrict__ w0,
                                                     const float* __restrict__ w1,
                                                     const float* __restrict__ w2,
                                                     const float* __restrict__ w3,
                                                     unsigned short* __restrict__ d0,
                                                     unsigned short* __restrict__ d1,
                                                     unsigned short* __restrict__ d2,
                                                     unsigned short* __restrict__ d3) {
    const int g = blockIdx.x >> 10;            // which weight (1024 blocks each)
    const float* src = g == 0 ? w0 : g == 1 ? w1 : g == 2 ? w2 : w3;
    unsigned short* dst = g == 0 ? d0 : g == 1 ? d1 : g == 2 ? d2 : d3;
    const int i = ((blockIdx.x & 1023) * 256 + threadIdx.x) * 4;
    f32x4 f = *(const f32x4*)(src + i);
    us4 o;
#pragma unroll
    for (int j = 0; j < 4; ++j) o[j] = f2bf(f[j]);
    *(us4*)(dst + i) = o;
}

// ---------------- GEMM: C[M,N] = A[M,K] @ W[N,K]^T ----------------
// M=8192, N=1024, K=1024. 128x128 tile, BK=32, 4 waves (each 64x64).
// Reg-prefetch (T14): next BK-chunk loads issued in the compute shadow.
// A_IS_F32: A is fp32 (converted to bf16 during LDS write), else bf16.
// OUT_MODE 0: bf16 [B,H,S,D]. OUT_MODE 1: fp32 [M,N]+bias.
// OUT_MODE 2: bf16 V^T kv-blocked [B,H,S/64,D,64].
template<int A_IS_F32, int OUT_MODE>
__global__ __launch_bounds__(256) void gemm_bt(const void* __restrict__ Aptr,
                                               const unsigned short* __restrict__ Wp,
                                               void* __restrict__ Cp,
                                               const float* __restrict__ bias) {
    constexpr int K = 1024;
    __shared__ unsigned short As[128][40];  // pad 32->40: 2-way (free) bank pattern
    __shared__ unsigned short Bs[128][40];
    const int tid = threadIdx.x;
    const int bm = blockIdx.x, bn = blockIdx.y;
    const int lane = tid & 63, wid = tid >> 6;
    const int lr = lane & 15, lg = lane >> 4;
    const int wr = wid >> 1, wc = wid & 1;
    const int srow = tid >> 1, shalf = tid & 1;

    f32x4 acc[4][4];
#pragma unroll
    for (int a = 0; a < 4; ++a)
#pragma unroll
        for (int b = 0; b < 4; ++b) acc[a][b] = (f32x4){0.f, 0.f, 0.f, 0.f};

    const size_t arow = (size_t)(bm * 128 + srow) * K + shalf * 16;
    const size_t brow = (size_t)(bn * 128 + srow) * K + shalf * 16;
    const float*          apF = (const float*)Aptr + arow;
    const unsigned short* apH = (const unsigned short*)Aptr + arow;
    const unsigned short* bp  = Wp + brow;

    // prefetch registers (prologue: chunk k0=0)
    f32x4 pa0, pa1, pa2, pa3;
    short8 pah0, pah1, pb0, pb1;
    if (A_IS_F32) {
        pa0 = *(const f32x4*)(apF);
        pa1 = *(const f32x4*)(apF + 4);
        pa2 = *(const f32x4*)(apF + 8);
        pa3 = *(const f32x4*)(apF + 12);
    } else {
        pah0 = *(const short8*)(apH);
        pah1 = *(const short8*)(apH + 8);
    }
    pb0 = *(const short8*)(bp);
    pb1 = *(const short8*)(bp + 8);

    for (int k0 = 0; k0 < K; k0 += 32) {
        __syncthreads();  // all waves done reading previous LDS contents
        if (A_IS_F32) {
            short8 p0, p1;
#pragma unroll
            for (int j = 0; j < 4; ++j) {
                p0[j]     = (short)f2bf(pa0[j]);
                p0[j + 4] = (short)f2bf(pa1[j]);
                p1[j]     = (short)f2bf(pa2[j]);
                p1[j + 4] = (short)f2bf(pa3[j]);
            }
            *(short8*)&As[srow][shalf * 16]     = p0;
            *(short8*)&As[srow][shalf * 16 + 8] = p1;
        } else {
            *(short8*)&As[srow][shalf * 16]     = pah0;
            *(short8*)&As[srow][shalf * 16 + 8] = pah1;
        }
        *(short8*)&Bs[srow][shalf * 16]     = pb0;
        *(short8*)&Bs[srow][shalf * 16 + 8] = pb1;
        __syncthreads();

        // issue next chunk's loads; they fly under the MFMA section below
        if (k0 + 32 < K) {
            const int kn = k0 + 32;
            if (A_IS_F32) {
                pa0 = *(const f32x4*)(apF + kn);
                pa1 = *(const f32x4*)(apF + kn + 4);
                pa2 = *(const f32x4*)(apF + kn + 8);
                pa3 = *(const f32x4*)(apF + kn + 12);
            } else {
                pah0 = *(const short8*)(apH + kn);
                pah1 = *(const short8*)(apH + kn + 8);
            }
            pb0 = *(const short8*)(bp + kn);
            pb1 = *(const short8*)(bp + kn + 8);
        }

        short8 af[4], bfr[4];
#pragma unroll
        for (int mi = 0; mi < 4; ++mi) af[mi]  = *(const short8*)&As[wr * 64 + mi * 16 + lr][lg * 8];
#pragma unroll
        for (int ni = 0; ni < 4; ++ni) bfr[ni] = *(const short8*)&Bs[wc * 64 + ni * 16 + lr][lg * 8];
#pragma unroll
        for (int mi = 0; mi < 4; ++mi)
#pragma unroll
            for (int ni = 0; ni < 4; ++ni)
                acc[mi][ni] = __builtin_amdgcn_mfma_f32_16x16x32_bf16(af[mi], bfr[ni], acc[mi][ni], 0, 0, 0);
    }

#pragma unroll
    for (int mi = 0; mi < 4; ++mi) {
#pragma unroll
        for (int ni = 0; ni < 4; ++ni) {
            const int n = bn * 128 + wc * 64 + ni * 16 + lr;
            if (OUT_MODE == 2) {
                // V^T kv-blocked: [B,H,S/64,D,64]; i -> s consecutive within a 64-block.
                const int m0 = bm * 128 + wr * 64 + mi * 16 + lg * 4;
                const int b = m0 >> 11, s0 = m0 & 2047;
                const int h = n >> 6, d = n & 63;
                us4 pk;
#pragma unroll
                for (int i = 0; i < 4; ++i) pk[i] = f2bf(acc[mi][ni][i]);
                const size_t idx = ((((size_t)b * NH + h) * (NS / 64) + (s0 >> 6)) * ND + d) * 64 + (s0 & 63);
                *(us4*)&((unsigned short*)Cp)[idx] = pk;
            } else {
#pragma unroll
                for (int i = 0; i < 4; ++i) {
                    const int m = bm * 128 + wr * 64 + mi * 16 + lg * 4 + i;
                    const float val = acc[mi][ni][i];
                    if (OUT_MODE == 0) {
                        const int b = m >> 11, s = m & 2047, h = n >> 6, d = n & 63;
                        ((unsigned short*)Cp)[(((size_t)b * NH + h) * NS + s) * ND + d] = f2bf(val);
                    } else {
                        ((float*)Cp)[(size_t)m * 1024 + n] = val + bias[n];
                    }
                }
            }
        }
    }
}

// ---------------- flash attention: 32x32 MFMA, P fully in-register ----------------
// grid (S/128, B*H), 256 threads. Wave w owns q rows qw..qw+31 (one 32-wide block).
// q,k: [B,H,S,D] bf16. vtt: [B,H,S/64,D,64] bf16 (V^T kv-blocked).
// Swapped operands with mfma_f32_32x32x16_bf16:
//   S^T = mfma(K,Q): C col = q = lane&31, row = kv = (reg&3)+8*(reg>>2)+4*(lane>>5)
//   -> all 64 kv of a q-row live in the lane pair (L, L^32): softmax = 1 shfl_xor(32).
// PV B-operand (col=q, k=8*(lane>>5)+j) built in-register: per 16-kv window,
// 4 packed bf16x2 words + 2 v_permlane32_swap_b32 (swap(wA,wC)->words 0,2;
// swap(wB,wD)->words 1,3). No P LDS round-trip at all.
__global__ __launch_bounds__(256, 3) void attn_kernel(const unsigned short* __restrict__ q,
                                                      const unsigned short* __restrict__ k,
                                                      const unsigned short* __restrict__ vtt,
                                                      unsigned short* __restrict__ o) {
    __shared__ unsigned short Kl[64][72];     // K tile [kv][d], pad 72 -> 8-phase b128 reads
    __shared__ unsigned short Vl[64][72];     // V^T tile [d][kv]
    const int tid = threadIdx.x;
    const int lane = tid & 63, wid = tid >> 6;
    const int l31 = lane & 31, hi = lane >> 5;
    const int bh = blockIdx.y;
    const int qw = blockIdx.x * 128 + wid * 32;   // this wave's first q row
    const size_t base = (size_t)bh * NS * ND;     // same stride for q/k and vtt

    // Q fragments (B-operand): col = q = l31, k = d = 16m + 8*hi + j
    short8 qf[4];
    {
        const unsigned short* qp = q + base + (size_t)(qw + l31) * ND + 8 * hi;
#pragma unroll
        for (int m = 0; m < 4; ++m) qf[m] = *(const short8*)(qp + 16 * m);
    }

    float m_run = -__builtin_inff(), l_run = 0.f;   // state for q-row l31 (pair-replicated)
    f32x16 oa0, oa1, fz;
#pragma unroll
    for (int i = 0; i < 16; ++i) { oa0[i] = 0.f; oa1[i] = 0.f; fz[i] = 0.f; }

    // staging: 8KB tile / 256 threads = 32B per thread, contiguous
    const int strow = tid >> 2, stcol = (tid & 3) * 16;
    const unsigned short* ks = k   + base + tid * 16;   // + kv0*ND per tile
    const unsigned short* vs = vtt + base + tid * 16;

    // prologue: prefetch tile kv0=0 into regs (T14)
    short8 kr0 = *(const short8*)(ks);
    short8 kr1 = *(const short8*)(ks + 8);
    short8 vr0 = *(const short8*)(vs);
    short8 vr1 = *(const short8*)(vs + 8);

    for (int kv0 = 0; kv0 < NS; kv0 += 64) {
        __syncthreads();                          // all waves done reading prev tile
        *(short8*)&Kl[strow][stcol]     = kr0;    // vmcnt wait lands here (1 tile later)
        *(short8*)&Kl[strow][stcol + 8] = kr1;
        *(short8*)&Vl[strow][stcol]     = vr0;
        *(short8*)&Vl[strow][stcol + 8] = vr1;
        __syncthreads();

        // issue next tile's loads; they fly under this tile's compute
        if (kv0 + 64 < NS) {
            const unsigned short* ks2 = ks + (size_t)(kv0 + 64) * ND;
            const unsigned short* vs2 = vs + (size_t)(kv0 + 64) * ND;
            kr0 = *(const short8*)(ks2);
            kr1 = *(const short8*)(ks2 + 8);
            vr0 = *(const short8*)(vs2);
            vr1 = *(const short8*)(vs2 + 8);
        }

        // S^T = K·Q^T: two 32-kv subtiles, K=64 via 4 chained mfma each
        f32x16 st0, st1;
        __builtin_amdgcn_s_setprio(1);
        {
            short8 kf;
            kf = *(const short8*)&Kl[l31][8 * hi];
            st0 = __builtin_amdgcn_mfma_f32_32x32x16_bf16(kf, qf[0], fz, 0, 0, 0);
            kf = *(const short8*)&Kl[l31][16 + 8 * hi];
            st0 = __builtin_amdgcn_mfma_f32_32x32x16_bf16(kf, qf[1], st0, 0, 0, 0);
            kf = *(const short8*)&Kl[l31][32 + 8 * hi];
            st0 = __builtin_amdgcn_mfma_f32_32x32x16_bf16(kf, qf[2], st0, 0, 0, 0);
            kf = *(const short8*)&Kl[l31][48 + 8 * hi];
            st0 = __builtin_amdgcn_mfma_f32_32x32x16_bf16(kf, qf[3], st0, 0, 0, 0);
            kf = *(const short8*)&Kl[32 + l31][8 * hi];
            st1 = __builtin_amdgcn_mfma_f32_32x32x16_bf16(kf, qf[0], fz, 0, 0, 0);
            kf = *(const short8*)&Kl[32 + l31][16 + 8 * hi];
            st1 = __builtin_amdgcn_mfma_f32_32x32x16_bf16(kf, qf[1], st1, 0, 0, 0);
            kf = *(const short8*)&Kl[32 + l31][32 + 8 * hi];
            st1 = __builtin_amdgcn_mfma_f32_32x32x16_bf16(kf, qf[2], st1, 0, 0, 0);
            kf = *(const short8*)&Kl[32 + l31][48 + 8 * hi];
            st1 = __builtin_amdgcn_mfma_f32_32x32x16_bf16(kf, qf[3], st1, 0, 0, 0);
        }
        __builtin_amdgcn_s_setprio(0);

        // online softmax (32 values/lane; lane pair (L, L^32) completes the row)
        float pm = st0[0];
#pragma unroll
        for (int i = 1; i < 16; ++i) pm = fmaxf(pm, st0[i]);
#pragma unroll
        for (int i = 0; i < 16; ++i) pm = fmaxf(pm, st1[i]);
        pm = fmaxf(pm, __shfl_xor(pm, 32, 64));
        if (!__all(pm <= m_run)) {   // T13(THR=0): skip-path multiplied by exactly 1.0 before
            const float mn = fmaxf(m_run, pm);
            const float alpha = __expf(m_run - mn);
            m_run = mn;
            l_run *= alpha;
#pragma unroll
            for (int i = 0; i < 16; ++i) { oa0[i] *= alpha; oa1[i] *= alpha; }
        }
        float rs = 0.f;
#pragma unroll
        for (int i = 0; i < 16; ++i) { st0[i] = __expf(st0[i] - m_run); rs += st0[i]; }
#pragma unroll
        for (int i = 0; i < 16; ++i) { st1[i] = __expf(st1[i] - m_run); rs += st1[i]; }
        rs += __shfl_xor(rs, 32, 64);
        l_run += rs;

        // P -> PV B-operand fragments, fully in-register (T12)
        short8 pf0, pf1, pf2, pf3;
#define MKPF(PF, SV, RB) { \
        unsigned int wa = packbf(SV[RB + 0], SV[RB + 1]); \
        unsigned int wb = packbf(SV[RB + 2], SV[RB + 3]); \
        unsigned int wc = packbf(SV[RB + 4], SV[RB + 5]); \
        unsigned int wd = packbf(SV[RB + 6], SV[RB + 7]); \
        asm("v_permlane32_swap_b32 %0, %1" : "+v"(wa), "+v"(wc)); \
        asm("v_permlane32_swap_b32 %0, %1" : "+v"(wb), "+v"(wd)); \
        u32x4 pw; pw[0] = wa; pw[1] = wb; pw[2] = wc; pw[3] = wd; \
        PF = __builtin_bit_cast(short8, pw); }
        MKPF(pf0, st0, 0)   // kv  0..15
        MKPF(pf1, st0, 8)   // kv 16..31
        MKPF(pf2, st1, 0)   // kv 32..47
        MKPF(pf3, st1, 8)   // kv 48..63
#undef MKPF

        // O^T += V^T · P^T  (A row = d, B col = q)
        __builtin_amdgcn_s_setprio(1);
        {
            short8 vf;
            vf = *(const short8*)&Vl[l31][8 * hi];
            oa0 = __builtin_amdgcn_mfma_f32_32x32x16_bf16(vf, pf0, oa0, 0, 0, 0);
            vf = *(const short8*)&Vl[l31][16 + 8 * hi];
            oa0 = __builtin_amdgcn_mfma_f32_32x32x16_bf16(vf, pf1, oa0, 0, 0, 0);
            vf = *(const short8*)&Vl[l31][32 + 8 * hi];
            oa0 = __builtin_amdgcn_mfma_f32_32x32x16_bf16(vf, pf2, oa0, 0, 0, 0);
            vf = *(const short8*)&Vl[l31][48 + 8 * hi];
            oa0 = __builtin_amdgcn_mfma_f32_32x32x16_bf16(vf, pf3, oa0, 0, 0, 0);
            vf = *(const short8*)&Vl[32 + l31][8 * hi];
            oa1 = __builtin_amdgcn_mfma_f32_32x32x16_bf16(vf, pf0, oa1, 0, 0, 0);
            vf = *(const short8*)&Vl[32 + l31][16 + 8 * hi];
            oa1 = __builtin_amdgcn_mfma_f32_32x32x16_bf16(vf, pf1, oa1, 0, 0, 0);
            vf = *(const short8*)&Vl[32 + l31][32 + 8 * hi];
            oa1 = __builtin_amdgcn_mfma_f32_32x32x16_bf16(vf, pf2, oa1, 0, 0, 0);
            vf = *(const short8*)&Vl[32 + l31][48 + 8 * hi];
            oa1 = __builtin_amdgcn_mfma_f32_32x32x16_bf16(vf, pf3, oa1, 0, 0, 0);
        }
        __builtin_amdgcn_s_setprio(0);
    }

    // epilogue: C reg r -> d = 32*t + 8*(r>>2) + 4*hi + (r&3); s = qw + l31
    const int b = bh >> 4, h = bh & 15;
    const float scl = 0.125f / l_run;   // softmax BEFORE scaling -> /8 here
    unsigned short* op = o + (((size_t)b * NS + (qw + l31)) * NH + h) * ND;
#pragma unroll
    for (int rq = 0; rq < 4; ++rq) {
        us4 p0, p1;
#pragma unroll
        for (int i = 0; i < 4; ++i) {
            p0[i] = f2bf(oa0[4 * rq + i] * scl);
            p1[i] = f2bf(oa1[4 * rq + i] * scl);
        }
        *(us4*)&op[8 * rq + 4 * hi]      = p0;
        *(us4*)&op[32 + 8 * rq + 4 * hi] = p1;
    }
}

extern "C" void kernel_launch(void* const* d_in, const int* in_sizes, int n_in,
                              void* d_out, int out_size, void* d_ws, size_t ws_size,
                              hipStream_t stream) {
    (void)in_sizes; (void)n_in; (void)out_size; (void)ws_size;
    const float* values  = (const float*)d_in[0];
    const float* keys    = (const float*)d_in[1];
    const float* queries = (const float*)d_in[2];
    const float* Wv = (const float*)d_in[3];
    const float* Wk = (const float*)d_in[4];
    const float* Wq = (const float*)d_in[5];
    const float* Wo = (const float*)d_in[6];
    const float* bo = (const float*)d_in[7];

    uint8_t* ws = (uint8_t*)d_ws;
    const size_t MB = (size_t)1 << 20;
    unsigned short* wvb = (unsigned short*)(ws + 0 * MB);
    unsigned short* wkb = (unsigned short*)(ws + 2 * MB);
    unsigned short* wqb = (unsigned short*)(ws + 4 * MB);
    unsigned short* wob = (unsigned short*)(ws + 6 * MB);
    unsigned short* qb  = (unsigned short*)(ws + 8 * MB);   // [B,H,S,D] bf16, 16 MB
    unsigned short* kb  = (unsigned short*)(ws + 24 * MB);  // [B,H,S,D] bf16
    unsigned short* vtb = (unsigned short*)(ws + 40 * MB);  // [B,H,S/64,D,64] bf16 (V^T kv-blocked)
    unsigned short* ab  = (unsigned short*)(ws + 56 * MB);  // [B,S,H,D] bf16, 16 MB

    cvt_w4_kernel<<<4096, 256, 0, stream>>>(Wv, Wk, Wq, Wo, wvb, wkb, wqb, wob);

    dim3 gg(64, 8);  // (M/128, N/128)
    gemm_bt<1, 0><<<gg, 256, 0, stream>>>(queries, wqb, qb,  nullptr);
    gemm_bt<1, 0><<<gg, 256, 0, stream>>>(keys,    wkb, kb,  nullptr);
    gemm_bt<1, 2><<<gg, 256, 0, stream>>>(values,  wvb, vtb, nullptr);

    attn_kernel<<<dim3(16, 64), 256, 0, stream>>>(qb, kb, vtb, ab);

    gemm_bt<0, 1><<<gg, 256, 0, stream>>>(ab, wob, d_out, bo);
}